// Round 1
// baseline (239.960 us; speedup 1.0000x reference)
//
#include <hip/hip_runtime.h>

typedef __attribute__((ext_vector_type(4))) float f32x4;
typedef __attribute__((ext_vector_type(8))) short s16x8;
typedef __attribute__((ext_vector_type(4))) unsigned int u32x4;

#define NB 4
#define CH 128
#define ICH 64
#define NSP 4096
#define KSPLIT 8
#define SEGK 512
#define LDK 72   // padded LDS row stride (bf16 elems): 144 B, 16B-aligned, 2-way banks

static __device__ __forceinline__ unsigned short f2bf(float f) {
  unsigned int u = __builtin_bit_cast(unsigned int, f);
  u += 0x7fffu + ((u >> 16) & 1u);   // RNE
  return (unsigned short)(u >> 16);
}
static __device__ __forceinline__ float bf2f(unsigned short h) {
  unsigned int u = ((unsigned int)h) << 16;
  return __builtin_bit_cast(float, u);
}

// ---------------- Kernel 1: theta/phi/g projections (+bias), bf16 outputs ----
// thetaT, phiT: [B][N][IC]  (A-operand-friendly);  g: [B][IC][N] (V^T-friendly)
__global__ __launch_bounds__(256) void k_proj(
    const float* __restrict__ x,
    const float* __restrict__ gw, const float* __restrict__ gbias,
    const float* __restrict__ tw, const float* __restrict__ tbias,
    const float* __restrict__ pw, const float* __restrict__ pbias,
    unsigned short* __restrict__ thetaT, unsigned short* __restrict__ phiT,
    unsigned short* __restrict__ gout)
{
  __shared__ float sx[CH * 64];   // x tile [c][n]
  __shared__ float st[64 * 65];   // transpose buffer (pad +1)
  const int b = blockIdx.y;
  const int n0 = blockIdx.x * 64;
  const int t = threadIdx.x;
  const float* xb = x + (size_t)b * CH * NSP;
#pragma unroll
  for (int i = 0; i < 8; ++i) {
    int idx = t + 256 * i;           // 2048 float4 chunks
    int c = idx >> 4, f4 = idx & 15;
    *(float4*)(sx + c * 64 + f4 * 4) = *(const float4*)(xb + (size_t)c * NSP + n0 + f4 * 4);
  }
  __syncthreads();
  const int n = t & 63;
  const int og = __builtin_amdgcn_readfirstlane(t >> 6);  // wave-uniform -> s_load for weights
  float at[16], ap[16], ag[16];
#pragma unroll
  for (int k = 0; k < 16; ++k) { at[k] = 0.f; ap[k] = 0.f; ag[k] = 0.f; }
#pragma unroll 4
  for (int c = 0; c < CH; ++c) {
    float xv = sx[c * 64 + n];
#pragma unroll
    for (int k = 0; k < 16; ++k) {
      int o = og * 16 + k;
      at[k] = fmaf(tw[o * CH + c], xv, at[k]);
      ap[k] = fmaf(pw[o * CH + c], xv, ap[k]);
      ag[k] = fmaf(gw[o * CH + c], xv, ag[k]);
    }
  }
  // theta: transpose via LDS, write [n][o] coalesced
#pragma unroll
  for (int k = 0; k < 16; ++k) st[n * 65 + og * 16 + k] = at[k] + tbias[og * 16 + k];
  __syncthreads();
  {
    int lane = t & 63, w = t >> 6;
#pragma unroll
    for (int r = 0; r < 16; ++r) {
      int nn = w * 16 + r;
      thetaT[((size_t)b * NSP + n0 + nn) * ICH + lane] = f2bf(st[nn * 65 + lane]);
    }
  }
  __syncthreads();
#pragma unroll
  for (int k = 0; k < 16; ++k) st[n * 65 + og * 16 + k] = ap[k] + pbias[og * 16 + k];
  __syncthreads();
  {
    int lane = t & 63, w = t >> 6;
#pragma unroll
    for (int r = 0; r < 16; ++r) {
      int nn = w * 16 + r;
      phiT[((size_t)b * NSP + n0 + nn) * ICH + lane] = f2bf(st[nn * 65 + lane]);
    }
  }
  // g: [o][n] layout, already coalesced
#pragma unroll
  for (int k = 0; k < 16; ++k) {
    int o = og * 16 + k;
    gout[((size_t)b * ICH + o) * NSP + n0 + n] = f2bf(ag[k] + gbias[o]);
  }
}

// ---------------- Kernel 2: flash attention partials (no max-sub needed) -----
// block = 2 waves; wave: 64 q rows (4x 16-row subtiles); K-tile 64; K-split 8
__global__ __launch_bounds__(128, 2) void k_attn(
    const unsigned short* __restrict__ thetaT,
    const unsigned short* __restrict__ phiT,
    const unsigned short* __restrict__ gmat,
    float* __restrict__ Opart, float* __restrict__ lpart)
{
  __shared__ unsigned short ldsK[64 * LDK];
  __shared__ unsigned short ldsV[64 * LDK];
  __shared__ unsigned short ldsP[2][64 * LDK];
  const int qt = blockIdx.x, b = blockIdx.y, seg = blockIdx.z;
  const int t = threadIdx.x;
  const int wave = t >> 6, lane = t & 63;
  const int l15 = lane & 15, quad = lane >> 4;
  const int q0 = qt * 128 + wave * 64;

  // Q A-frags: lane holds Q[m=lane&15][k=quad*8+j (+32*ks)]  [verified m120]
  s16x8 aq[4][2];
  const unsigned short* th = thetaT + ((size_t)b * NSP + q0) * ICH;
#pragma unroll
  for (int qs = 0; qs < 4; ++qs)
#pragma unroll
    for (int ks = 0; ks < 2; ++ks)
      aq[qs][ks] = __builtin_bit_cast(s16x8,
          *(const u32x4*)(th + (qs * 16 + l15) * ICH + ks * 32 + quad * 8));

  f32x4 Oacc[4][4];
  float lacc[4][4];
#pragma unroll
  for (int i = 0; i < 4; ++i)
#pragma unroll
    for (int j = 0; j < 4; ++j) { Oacc[i][j] = (f32x4){0.f, 0.f, 0.f, 0.f}; lacc[i][j] = 0.f; }

  const unsigned short* ph = phiT + (size_t)b * NSP * ICH;
  const unsigned short* gb = gmat + (size_t)b * ICH * NSP;
  const int k0 = seg * SEGK;

  for (int kt = 0; kt < SEGK / 64; ++kt) {
    const int key0 = k0 + kt * 64;
    __syncthreads();
    // stage K[key][d] and V^T[d][key] (g's native layout), 16B chunks
#pragma unroll
    for (int i = 0; i < 4; ++i) {
      int idx = t + 128 * i;            // 512 chunks each
      int row = idx >> 3, c16 = idx & 7;
      *(u32x4*)(&ldsK[row * LDK + c16 * 8]) =
          *(const u32x4*)(ph + (size_t)(key0 + row) * ICH + c16 * 8);
      *(u32x4*)(&ldsV[row * LDK + c16 * 8]) =
          *(const u32x4*)(gb + (size_t)row * NSP + key0 + c16 * 8);
    }
    __syncthreads();

    // K B-frags: lane holds K[key=kc*16+l15][d=quad*8+j+32ks]
    s16x8 bk[4][2];
#pragma unroll
    for (int kc = 0; kc < 4; ++kc)
#pragma unroll
      for (int ks = 0; ks < 2; ++ks)
        bk[kc][ks] = *(const s16x8*)(&ldsK[(kc * 16 + l15) * LDK + ks * 32 + quad * 8]);

    unsigned short* myP = &ldsP[wave][0];
#pragma unroll
    for (int qs = 0; qs < 4; ++qs) {
      f32x4 s[4];
#pragma unroll
      for (int kc = 0; kc < 4; ++kc) {
        f32x4 acc = (f32x4){0.f, 0.f, 0.f, 0.f};
        acc = __builtin_amdgcn_mfma_f32_16x16x32_bf16(aq[qs][0], bk[kc][0], acc, 0, 0, 0);
        acc = __builtin_amdgcn_mfma_f32_16x16x32_bf16(aq[qs][1], bk[kc][1], acc, 0, 0, 0);
        s[kc] = acc;
      }
      // exp (scores bounded -> no max subtraction) + row-sum for l
      float tmp[4] = {0.f, 0.f, 0.f, 0.f};
#pragma unroll
      for (int kc = 0; kc < 4; ++kc)
#pragma unroll
        for (int r = 0; r < 4; ++r) {
          float e = __expf(s[kc][r]);
          s[kc][r] = e;
          tmp[r] += e;
        }
#pragma unroll
      for (int m = 1; m < 16; m <<= 1)
#pragma unroll
        for (int r = 0; r < 4; ++r) tmp[r] += __shfl_xor(tmp[r], m, 64);
#pragma unroll
      for (int r = 0; r < 4; ++r) lacc[qs][r] += tmp[r];
      // P -> per-wave LDS (C-layout: row=quad*4+r, col=kc*16+l15)
#pragma unroll
      for (int kc = 0; kc < 4; ++kc)
#pragma unroll
        for (int r = 0; r < 4; ++r)
          myP[(qs * 16 + quad * 4 + r) * LDK + kc * 16 + l15] = f2bf(s[kc][r]);
    }

    // V B-frags: lane holds V[key=quad*8+j+32ks][d=ds*16+l15] = ldsV[d][key]
    s16x8 bv[2][4];
#pragma unroll
    for (int ks = 0; ks < 2; ++ks)
#pragma unroll
      for (int ds = 0; ds < 4; ++ds)
        bv[ks][ds] = *(const s16x8*)(&ldsV[(ds * 16 + l15) * LDK + ks * 32 + quad * 8]);
#pragma unroll
    for (int qs = 0; qs < 4; ++qs)
#pragma unroll
      for (int ks = 0; ks < 2; ++ks) {
        s16x8 ap2 = *(const s16x8*)(&myP[(qs * 16 + l15) * LDK + ks * 32 + quad * 8]);
#pragma unroll
        for (int ds = 0; ds < 4; ++ds)
          Oacc[qs][ds] = __builtin_amdgcn_mfma_f32_16x16x32_bf16(ap2, bv[ks][ds], Oacc[qs][ds], 0, 0, 0);
      }
  }

  // unnormalized partials out
  float* Ob = Opart + (((size_t)seg * NB + b) * NSP + q0) * ICH;
#pragma unroll
  for (int qs = 0; qs < 4; ++qs)
#pragma unroll
    for (int ds = 0; ds < 4; ++ds)
#pragma unroll
      for (int r = 0; r < 4; ++r)
        Ob[(qs * 16 + quad * 4 + r) * ICH + ds * 16 + l15] = Oacc[qs][ds][r];
  if (l15 == 0) {
    float* lb = lpart + ((size_t)seg * NB + b) * NSP + q0;
#pragma unroll
    for (int qs = 0; qs < 4; ++qs)
#pragma unroll
      for (int r = 0; r < 4; ++r)
        lb[qs * 16 + quad * 4 + r] = lacc[qs][r];
  }
}

// ---------------- Kernel 2b: combine K-split partials -> y bf16 [B][N][IC] ---
__global__ __launch_bounds__(256) void k_combine(
    const float* __restrict__ Opart, const float* __restrict__ lpart,
    unsigned short* __restrict__ y)
{
  int idx = blockIdx.x * 256 + threadIdx.x;   // B*N*IC = 1M
  int d = idx & 63;
  int q = (idx >> 6) & (NSP - 1);
  int b = idx >> 18;
  float o = 0.f, l = 0.f;
#pragma unroll
  for (int s = 0; s < KSPLIT; ++s) {
    o += Opart[(((size_t)s * NB + b) * NSP + q) * ICH + d];
    l += lpart[((size_t)s * NB + b) * NSP + q];
  }
  y[idx] = f2bf(o / l);
}

// ---------------- Kernel 3a: WyT[n][co] = y[n][:] . Ww[co][:] (MFMA) + stats -
__global__ __launch_bounds__(256) void k_wy(
    const unsigned short* __restrict__ y,
    const float* __restrict__ Ww,
    float* __restrict__ WyT, float* __restrict__ stat)
{
  const int b = blockIdx.y;
  const int nt = blockIdx.x;
  const int t = threadIdx.x;
  const int wave = t >> 6, lane = t & 63;
  const int l15 = lane & 15, quad = lane >> 4;
  // Ww B-frags (bf16), loaded once: lane holds Ww[co=cc*16+l15][ic=quad*8+j+32ks]
  s16x8 bw[8][2];
#pragma unroll
  for (int cc = 0; cc < 8; ++cc)
#pragma unroll
    for (int ks = 0; ks < 2; ++ks) {
      const float* wp = Ww + (cc * 16 + l15) * ICH + ks * 32 + quad * 8;
      s16x8 e;
#pragma unroll
      for (int j = 0; j < 8; ++j) e[j] = (short)f2bf(wp[j]);
      bw[cc][ks] = e;
    }
  float sums[8], sq[8];
#pragma unroll
  for (int cc = 0; cc < 8; ++cc) { sums[cc] = 0.f; sq[cc] = 0.f; }
  const unsigned short* yb = y + (size_t)b * NSP * ICH;
#pragma unroll
  for (int ns = 0; ns < 4; ++ns) {
    const int n0 = nt * 256 + wave * 64 + ns * 16;
    s16x8 ay[2];
#pragma unroll
    for (int ks = 0; ks < 2; ++ks)
      ay[ks] = __builtin_bit_cast(s16x8,
          *(const u32x4*)(yb + (size_t)(n0 + l15) * ICH + ks * 32 + quad * 8));
#pragma unroll
    for (int cc = 0; cc < 8; ++cc) {
      f32x4 acc = (f32x4){0.f, 0.f, 0.f, 0.f};
      acc = __builtin_amdgcn_mfma_f32_16x16x32_bf16(ay[0], bw[cc][0], acc, 0, 0, 0);
      acc = __builtin_amdgcn_mfma_f32_16x16x32_bf16(ay[1], bw[cc][1], acc, 0, 0, 0);
      float* wout = WyT + (size_t)(b * NSP + n0 + quad * 4) * CH + cc * 16 + l15;
#pragma unroll
      for (int r = 0; r < 4; ++r) {
        float v = acc[r];
        sums[cc] += v;
        sq[cc] += v * v;
        wout[r * CH] = v;
      }
    }
  }
#pragma unroll
  for (int cc = 0; cc < 8; ++cc) {
    sums[cc] += __shfl_xor(sums[cc], 16, 64);
    sums[cc] += __shfl_xor(sums[cc], 32, 64);
    sq[cc] += __shfl_xor(sq[cc], 16, 64);
    sq[cc] += __shfl_xor(sq[cc], 32, 64);
  }
  if (quad == 0) {
#pragma unroll
    for (int cc = 0; cc < 8; ++cc) {
      atomicAdd(&stat[(b * CH + cc * 16 + l15) * 2 + 0], sums[cc]);
      atomicAdd(&stat[(b * CH + cc * 16 + l15) * 2 + 1], sq[cc]);
    }
  }
}

// ---------------- Kernel 3b: InstanceNorm + residual, out [B][C][N] ---------
__global__ __launch_bounds__(256) void k_norm(
    const float* __restrict__ WyT, const float* __restrict__ stat,
    const float* __restrict__ x, float* __restrict__ out)
{
  __shared__ float sWy[32 * 132];   // [n][co], pad stride 132
  const int nt = blockIdx.x;        // 0..127, 32 n each
  const int b = blockIdx.y;
  const int t = threadIdx.x;
  const int n0 = nt * 32;
#pragma unroll
  for (int i = 0; i < 4; ++i) {
    int idx = t + 256 * i;
    int row = idx >> 5, c4 = idx & 31;
    *(float4*)(&sWy[row * 132 + c4 * 4]) =
        *(const float4*)(WyT + (size_t)(b * NSP + n0 + row) * CH + c4 * 4);
  }
  __syncthreads();
#pragma unroll
  for (int j = 0; j < 4; ++j) {
    int u = t + 256 * j;
    int co = u >> 3, nq = u & 7;
    float s = stat[(b * CH + co) * 2 + 0];
    float ss = stat[(b * CH + co) * 2 + 1];
    float mean = s * (1.f / NSP);
    float var = ss * (1.f / NSP) - mean * mean;   // biased, matches jnp.var
    float rs = rsqrtf(var + 1e-5f);
    float4 xv = *(const float4*)(x + (size_t)(b * CH + co) * NSP + n0 + nq * 4);
    float4 ov;
    ov.x = xv.x + (sWy[(nq * 4 + 0) * 132 + co] - mean) * rs;
    ov.y = xv.y + (sWy[(nq * 4 + 1) * 132 + co] - mean) * rs;
    ov.z = xv.z + (sWy[(nq * 4 + 2) * 132 + co] - mean) * rs;
    ov.w = xv.w + (sWy[(nq * 4 + 3) * 132 + co] - mean) * rs;
    *(float4*)(out + (size_t)(b * CH + co) * NSP + n0 + nq * 4) = ov;
  }
}

extern "C" void kernel_launch(void* const* d_in, const int* in_sizes, int n_in,
                              void* d_out, int out_size, void* d_ws, size_t ws_size,
                              hipStream_t stream)
{
  const float* x  = (const float*)d_in[0];
  const float* gw = (const float*)d_in[1];
  const float* gb = (const float*)d_in[2];
  const float* tw = (const float*)d_in[3];
  const float* tb = (const float*)d_in[4];
  const float* pw = (const float*)d_in[5];
  const float* pb = (const float*)d_in[6];
  const float* Ww = (const float*)d_in[7];
  // d_in[8] = W_b: constant per-channel shift, canceled by InstanceNorm -> unused
  float* out = (float*)d_out;
  char* ws = (char*)d_ws;
  // workspace layout (~50 MB)
  unsigned short* thetaT = (unsigned short*)(ws);                      // 2 MB
  unsigned short* phiT   = (unsigned short*)(ws + (2ull << 20));       // 2 MB
  unsigned short* gmat   = (unsigned short*)(ws + (4ull << 20));       // 2 MB
  unsigned short* ybuf   = (unsigned short*)(ws + (6ull << 20));       // 2 MB
  float* WyT   = (float*)(ws + (8ull << 20));                          // 8 MB
  float* stat  = (float*)(ws + (16ull << 20));                         // 4 KB
  float* Opart = (float*)(ws + (17ull << 20));                         // 32 MB
  float* lpart = (float*)(ws + (49ull << 20));                         // 512 KB

  hipMemsetAsync(stat, 0, NB * CH * 2 * sizeof(float), stream);
  k_proj<<<dim3(64, 4), 256, 0, stream>>>(x, gw, gb, tw, tb, pw, pb, thetaT, phiT, gmat);
  k_attn<<<dim3(32, 4, 8), 128, 0, stream>>>(thetaT, phiT, gmat, Opart, lpart);
  k_combine<<<dim3((NB * NSP * ICH) / 256), 256, 0, stream>>>(Opart, lpart, ybuf);
  k_wy<<<dim3(16, 4), 256, 0, stream>>>(ybuf, Ww, WyT, stat);
  k_norm<<<dim3(128, 4), 256, 0, stream>>>(WyT, stat, x, out);
}

// Round 2
// 156.982 us; speedup vs baseline: 1.5286x; 1.5286x over previous
//
#include <hip/hip_runtime.h>

typedef __attribute__((ext_vector_type(4))) float f32x4;
typedef __attribute__((ext_vector_type(8))) short s16x8;
typedef __attribute__((ext_vector_type(4))) short s16x4;
typedef __attribute__((ext_vector_type(4))) unsigned int u32x4;

#define NB 4
#define CH 128
#define ICH 64
#define NSP 4096
#define KSPLIT 8
#define SEGK 512
#define LDK 72    // k_attn LDS row stride (bf16): 144 B, 16B-aligned, 2-way banks
#define LDW 136   // k_proj W LDS stride (bf16): 272 B, 8B-aligned b64 frags, 2-way banks

static __device__ __forceinline__ unsigned short f2bf(float f) {
  unsigned int u = __builtin_bit_cast(unsigned int, f);
  u += 0x7fffu + ((u >> 16) & 1u);   // RNE
  return (unsigned short)(u >> 16);
}

// ---------------- Kernel 1: one projection per block (MFMA) ------------------
// z=0: thetaT [B][N][IC]; z=1: phiT [B][N][IC]; z=2: g [B][IC][N]
// out[n][o] = sum_c x[c][n] * W[o][c] + bias[o]
__global__ __launch_bounds__(256) void k_proj(
    const float* __restrict__ x,
    const float* __restrict__ gw, const float* __restrict__ gbias,
    const float* __restrict__ tw, const float* __restrict__ tbias,
    const float* __restrict__ pw, const float* __restrict__ pbias,
    unsigned short* __restrict__ thetaT, unsigned short* __restrict__ phiT,
    unsigned short* __restrict__ gout)
{
  __shared__ __align__(16) float sxf[CH * 65];          // x tile [c][n], pad 65
  __shared__ __align__(16) unsigned short sW[ICH * LDW]; // W bf16 [o][c]
  const int b = blockIdx.y, z = blockIdx.z;
  const int n0 = blockIdx.x * 64;
  const int t = threadIdx.x;
  const float* Wz = (z == 0) ? tw : (z == 1) ? pw : gw;
  const float* Bz = (z == 0) ? tbias : (z == 1) ? pbias : gbias;
  const float* xb = x + (size_t)b * CH * NSP;
  // stage x tile [c][n] fp32 (coalesced; 2-way LDS bank alias only)
#pragma unroll
  for (int i = 0; i < 8; ++i) {
    int idx = t + 256 * i;             // 2048 float4 chunks
    int c = idx >> 4, ch = idx & 15;
    *(float4*)(sxf + c * 65 + ch * 4) = *(const float4*)(xb + (size_t)c * NSP + n0 + ch * 4);
  }
  // stage W -> bf16 LDS [o][c] stride LDW
#pragma unroll
  for (int i = 0; i < 8; ++i) {
    int idx = t + 256 * i;             // 2048 float4 chunks (64*128 floats)
    int o = idx >> 5, col = (idx & 31) * 4;
    float4 wv = *(const float4*)(Wz + o * CH + col);
    unsigned int p0 = (unsigned int)f2bf(wv.x) | ((unsigned int)f2bf(wv.y) << 16);
    unsigned int p1 = (unsigned int)f2bf(wv.z) | ((unsigned int)f2bf(wv.w) << 16);
    *(unsigned int*)(&sW[o * LDW + col]) = p0;
    *(unsigned int*)(&sW[o * LDW + col + 2]) = p1;
  }
  __syncthreads();

  const int wave = t >> 6, lane = t & 63;
  const int l15 = lane & 15, quad = lane >> 4;
  const int nw = wave * 16;            // 16-n subtile per wave
  // A-frags: lane holds x^T[n=nw+l15][c=kc*32+quad*8+j]
  s16x8 aq[4];
#pragma unroll
  for (int kc = 0; kc < 4; ++kc) {
#pragma unroll
    for (int j = 0; j < 8; ++j)
      aq[kc][j] = (short)f2bf(sxf[(kc * 32 + quad * 8 + j) * 65 + nw + l15]);
  }
  __syncthreads();   // sxf reads done -> safe to alias for g transpose

  unsigned short* ldsT = (unsigned short*)sxf;  // g transpose buffer [n][o] stride LDK

#pragma unroll
  for (int osub = 0; osub < 4; ++osub) {
    f32x4 acc = (f32x4){0.f, 0.f, 0.f, 0.f};
#pragma unroll
    for (int kc = 0; kc < 4; ++kc) {
      const unsigned short* wp = &sW[(osub * 16 + l15) * LDW + kc * 32 + quad * 8];
      s16x4 lo = *(const s16x4*)(wp);
      s16x4 hi = *(const s16x4*)(wp + 4);
      s16x8 bw = __builtin_shufflevector(lo, hi, 0, 1, 2, 3, 4, 5, 6, 7);
      acc = __builtin_amdgcn_mfma_f32_16x16x32_bf16(aq[kc], bw, acc, 0, 0, 0);
    }
    float bv = Bz[osub * 16 + l15];
    if (z < 2) {
      unsigned short* outp = (z == 0) ? thetaT : phiT;
#pragma unroll
      for (int r = 0; r < 4; ++r)
        outp[((size_t)b * NSP + n0 + nw + quad * 4 + r) * ICH + osub * 16 + l15] =
            f2bf(acc[r] + bv);
    } else {
#pragma unroll
      for (int r = 0; r < 4; ++r)
        ldsT[(nw + quad * 4 + r) * LDK + osub * 16 + l15] = f2bf(acc[r] + bv);
    }
  }
  if (z == 2) {
    __syncthreads();
    // coalesced write g[o][n]: thread t -> o=t>>2, n-chunk=(t&3)*16
    int o = t >> 2, chunk = t & 3;
    unsigned short vv[16];
#pragma unroll
    for (int jj = 0; jj < 16; ++jj) vv[jj] = ldsT[(chunk * 16 + jj) * LDK + o];
    unsigned int words[8];
#pragma unroll
    for (int i = 0; i < 8; ++i)
      words[i] = (unsigned int)vv[2 * i] | ((unsigned int)vv[2 * i + 1] << 16);
    unsigned short* gp = gout + ((size_t)b * ICH + o) * NSP + n0 + chunk * 16;
    *(u32x4*)(gp) = (u32x4){words[0], words[1], words[2], words[3]};
    *(u32x4*)(gp + 8) = (u32x4){words[4], words[5], words[6], words[7]};
  }
}

// ---------------- Kernel 2: flash attention partials (no max-sub needed) -----
// block = 2 waves; wave: 64 q rows (4x 16-row subtiles); K-tile 64; K-split 8
__global__ __launch_bounds__(128, 2) void k_attn(
    const unsigned short* __restrict__ thetaT,
    const unsigned short* __restrict__ phiT,
    const unsigned short* __restrict__ gmat,
    float* __restrict__ Opart, float* __restrict__ lpart)
{
  __shared__ unsigned short ldsK[64 * LDK];
  __shared__ unsigned short ldsV[64 * LDK];
  __shared__ unsigned short ldsP[2][64 * LDK];
  const int qt = blockIdx.x, b = blockIdx.y, seg = blockIdx.z;
  const int t = threadIdx.x;
  const int wave = t >> 6, lane = t & 63;
  const int l15 = lane & 15, quad = lane >> 4;
  const int q0 = qt * 128 + wave * 64;

  // Q A-frags: lane holds Q[m=lane&15][k=quad*8+j (+32*ks)]  [verified m120]
  s16x8 aq[4][2];
  const unsigned short* th = thetaT + ((size_t)b * NSP + q0) * ICH;
#pragma unroll
  for (int qs = 0; qs < 4; ++qs)
#pragma unroll
    for (int ks = 0; ks < 2; ++ks)
      aq[qs][ks] = __builtin_bit_cast(s16x8,
          *(const u32x4*)(th + (qs * 16 + l15) * ICH + ks * 32 + quad * 8));

  f32x4 Oacc[4][4];
  float lacc[4][4];
#pragma unroll
  for (int i = 0; i < 4; ++i)
#pragma unroll
    for (int j = 0; j < 4; ++j) { Oacc[i][j] = (f32x4){0.f, 0.f, 0.f, 0.f}; lacc[i][j] = 0.f; }

  const unsigned short* ph = phiT + (size_t)b * NSP * ICH;
  const unsigned short* gb = gmat + (size_t)b * ICH * NSP;
  const int k0 = seg * SEGK;

  for (int kt = 0; kt < SEGK / 64; ++kt) {
    const int key0 = k0 + kt * 64;
    __syncthreads();
    // stage K[key][d] and V^T[d][key] (g's native layout), 16B chunks
#pragma unroll
    for (int i = 0; i < 4; ++i) {
      int idx = t + 128 * i;            // 512 chunks each
      int row = idx >> 3, c16 = idx & 7;
      *(u32x4*)(&ldsK[row * LDK + c16 * 8]) =
          *(const u32x4*)(ph + (size_t)(key0 + row) * ICH + c16 * 8);
      *(u32x4*)(&ldsV[row * LDK + c16 * 8]) =
          *(const u32x4*)(gb + (size_t)row * NSP + key0 + c16 * 8);
    }
    __syncthreads();

    // K B-frags: lane holds K[key=kc*16+l15][d=quad*8+j+32ks]
    s16x8 bk[4][2];
#pragma unroll
    for (int kc = 0; kc < 4; ++kc)
#pragma unroll
      for (int ks = 0; ks < 2; ++ks)
        bk[kc][ks] = *(const s16x8*)(&ldsK[(kc * 16 + l15) * LDK + ks * 32 + quad * 8]);

    unsigned short* myP = &ldsP[wave][0];
#pragma unroll
    for (int qs = 0; qs < 4; ++qs) {
      f32x4 s[4];
#pragma unroll
      for (int kc = 0; kc < 4; ++kc) {
        f32x4 acc = (f32x4){0.f, 0.f, 0.f, 0.f};
        acc = __builtin_amdgcn_mfma_f32_16x16x32_bf16(aq[qs][0], bk[kc][0], acc, 0, 0, 0);
        acc = __builtin_amdgcn_mfma_f32_16x16x32_bf16(aq[qs][1], bk[kc][1], acc, 0, 0, 0);
        s[kc] = acc;
      }
      // exp (scores bounded -> no max subtraction) + row-sum for l
      float tmp[4] = {0.f, 0.f, 0.f, 0.f};
#pragma unroll
      for (int kc = 0; kc < 4; ++kc)
#pragma unroll
        for (int r = 0; r < 4; ++r) {
          float e = __expf(s[kc][r]);
          s[kc][r] = e;
          tmp[r] += e;
        }
#pragma unroll
      for (int m = 1; m < 16; m <<= 1)
#pragma unroll
        for (int r = 0; r < 4; ++r) tmp[r] += __shfl_xor(tmp[r], m, 64);
#pragma unroll
      for (int r = 0; r < 4; ++r) lacc[qs][r] += tmp[r];
      // P -> per-wave LDS (C-layout: row=quad*4+r, col=kc*16+l15)
#pragma unroll
      for (int kc = 0; kc < 4; ++kc)
#pragma unroll
        for (int r = 0; r < 4; ++r)
          myP[(qs * 16 + quad * 4 + r) * LDK + kc * 16 + l15] = f2bf(s[kc][r]);
    }

    // V B-frags: lane holds V[key=quad*8+j+32ks][d=ds*16+l15] = ldsV[d][key]
    s16x8 bv[2][4];
#pragma unroll
    for (int ks = 0; ks < 2; ++ks)
#pragma unroll
      for (int ds = 0; ds < 4; ++ds)
        bv[ks][ds] = *(const s16x8*)(&ldsV[(ds * 16 + l15) * LDK + ks * 32 + quad * 8]);
#pragma unroll
    for (int qs = 0; qs < 4; ++qs)
#pragma unroll
      for (int ks = 0; ks < 2; ++ks) {
        s16x8 ap2 = *(const s16x8*)(&myP[(qs * 16 + l15) * LDK + ks * 32 + quad * 8]);
#pragma unroll
        for (int ds = 0; ds < 4; ++ds)
          Oacc[qs][ds] = __builtin_amdgcn_mfma_f32_16x16x32_bf16(ap2, bv[ks][ds], Oacc[qs][ds], 0, 0, 0);
      }
  }

  // unnormalized partials out
  float* Ob = Opart + (((size_t)seg * NB + b) * NSP + q0) * ICH;
#pragma unroll
  for (int qs = 0; qs < 4; ++qs)
#pragma unroll
    for (int ds = 0; ds < 4; ++ds)
#pragma unroll
      for (int r = 0; r < 4; ++r)
        Ob[(qs * 16 + quad * 4 + r) * ICH + ds * 16 + l15] = Oacc[qs][ds][r];
  if (l15 == 0) {
    float* lb = lpart + ((size_t)seg * NB + b) * NSP + q0;
#pragma unroll
    for (int qs = 0; qs < 4; ++qs)
#pragma unroll
      for (int r = 0; r < 4; ++r)
        lb[qs * 16 + quad * 4 + r] = lacc[qs][r];
  }
}

// ---------------- Kernel 2b: combine K-split partials -> y bf16 [B][N][IC] ---
__global__ __launch_bounds__(256) void k_combine(
    const float* __restrict__ Opart, const float* __restrict__ lpart,
    unsigned short* __restrict__ y)
{
  int idx = blockIdx.x * 256 + threadIdx.x;   // B*N*IC = 1M
  int d = idx & 63;
  int q = (idx >> 6) & (NSP - 1);
  int b = idx >> 18;
  float o = 0.f, l = 0.f;
#pragma unroll
  for (int s = 0; s < KSPLIT; ++s) {
    o += Opart[(((size_t)s * NB + b) * NSP + q) * ICH + d];
    l += lpart[((size_t)s * NB + b) * NSP + q];
  }
  y[idx] = f2bf(o / l);
}

// ---------------- Kernel 3a: WyT[n][co] = y[n][:] . Ww[co][:] (MFMA) + stats -
__global__ __launch_bounds__(256) void k_wy(
    const unsigned short* __restrict__ y,
    const float* __restrict__ Ww,
    float* __restrict__ WyT, float* __restrict__ stat)
{
  const int b = blockIdx.y;
  const int nt = blockIdx.x;
  const int t = threadIdx.x;
  const int wave = t >> 6, lane = t & 63;
  const int l15 = lane & 15, quad = lane >> 4;
  // Ww B-frags (bf16), loaded once: lane holds Ww[co=cc*16+l15][ic=quad*8+j+32ks]
  s16x8 bw[8][2];
#pragma unroll
  for (int cc = 0; cc < 8; ++cc)
#pragma unroll
    for (int ks = 0; ks < 2; ++ks) {
      const float* wp = Ww + (cc * 16 + l15) * ICH + ks * 32 + quad * 8;
      s16x8 e;
#pragma unroll
      for (int j = 0; j < 8; ++j) e[j] = (short)f2bf(wp[j]);
      bw[cc][ks] = e;
    }
  float sums[8], sq[8];
#pragma unroll
  for (int cc = 0; cc < 8; ++cc) { sums[cc] = 0.f; sq[cc] = 0.f; }
  const unsigned short* yb = y + (size_t)b * NSP * ICH;
#pragma unroll
  for (int ns = 0; ns < 4; ++ns) {
    const int n0 = nt * 256 + wave * 64 + ns * 16;
    s16x8 ay[2];
#pragma unroll
    for (int ks = 0; ks < 2; ++ks)
      ay[ks] = __builtin_bit_cast(s16x8,
          *(const u32x4*)(yb + (size_t)(n0 + l15) * ICH + ks * 32 + quad * 8));
#pragma unroll
    for (int cc = 0; cc < 8; ++cc) {
      f32x4 acc = (f32x4){0.f, 0.f, 0.f, 0.f};
      acc = __builtin_amdgcn_mfma_f32_16x16x32_bf16(ay[0], bw[cc][0], acc, 0, 0, 0);
      acc = __builtin_amdgcn_mfma_f32_16x16x32_bf16(ay[1], bw[cc][1], acc, 0, 0, 0);
      float* wout = WyT + (size_t)(b * NSP + n0 + quad * 4) * CH + cc * 16 + l15;
#pragma unroll
      for (int r = 0; r < 4; ++r) {
        float v = acc[r];
        sums[cc] += v;
        sq[cc] += v * v;
        wout[r * CH] = v;
      }
    }
  }
#pragma unroll
  for (int cc = 0; cc < 8; ++cc) {
    sums[cc] += __shfl_xor(sums[cc], 16, 64);
    sums[cc] += __shfl_xor(sums[cc], 32, 64);
    sq[cc] += __shfl_xor(sq[cc], 16, 64);
    sq[cc] += __shfl_xor(sq[cc], 32, 64);
  }
  if (quad == 0) {
#pragma unroll
    for (int cc = 0; cc < 8; ++cc) {
      atomicAdd(&stat[(b * CH + cc * 16 + l15) * 2 + 0], sums[cc]);
      atomicAdd(&stat[(b * CH + cc * 16 + l15) * 2 + 1], sq[cc]);
    }
  }
}

// ---------------- Kernel 3b: InstanceNorm + residual, out [B][C][N] ---------
__global__ __launch_bounds__(256) void k_norm(
    const float* __restrict__ WyT, const float* __restrict__ stat,
    const float* __restrict__ x, float* __restrict__ out)
{
  __shared__ float sWy[32 * 132];   // [n][co], pad stride 132
  const int nt = blockIdx.x;        // 0..127, 32 n each
  const int b = blockIdx.y;
  const int t = threadIdx.x;
  const int n0 = nt * 32;
#pragma unroll
  for (int i = 0; i < 4; ++i) {
    int idx = t + 256 * i;
    int row = idx >> 5, c4 = idx & 31;
    *(float4*)(&sWy[row * 132 + c4 * 4]) =
        *(const float4*)(WyT + (size_t)(b * NSP + n0 + row) * CH + c4 * 4);
  }
  __syncthreads();
#pragma unroll
  for (int j = 0; j < 4; ++j) {
    int u = t + 256 * j;
    int co = u >> 3, nq = u & 7;
    float s = stat[(b * CH + co) * 2 + 0];
    float ss = stat[(b * CH + co) * 2 + 1];
    float mean = s * (1.f / NSP);
    float var = ss * (1.f / NSP) - mean * mean;   // biased, matches jnp.var
    float rs = rsqrtf(var + 1e-5f);
    float4 xv = *(const float4*)(x + (size_t)(b * CH + co) * NSP + n0 + nq * 4);
    float4 ov;
    ov.x = xv.x + (sWy[(nq * 4 + 0) * 132 + co] - mean) * rs;
    ov.y = xv.y + (sWy[(nq * 4 + 1) * 132 + co] - mean) * rs;
    ov.z = xv.z + (sWy[(nq * 4 + 2) * 132 + co] - mean) * rs;
    ov.w = xv.w + (sWy[(nq * 4 + 3) * 132 + co] - mean) * rs;
    *(float4*)(out + (size_t)(b * CH + co) * NSP + n0 + nq * 4) = ov;
  }
}

extern "C" void kernel_launch(void* const* d_in, const int* in_sizes, int n_in,
                              void* d_out, int out_size, void* d_ws, size_t ws_size,
                              hipStream_t stream)
{
  const float* x  = (const float*)d_in[0];
  const float* gw = (const float*)d_in[1];
  const float* gb = (const float*)d_in[2];
  const float* tw = (const float*)d_in[3];
  const float* tb = (const float*)d_in[4];
  const float* pw = (const float*)d_in[5];
  const float* pb = (const float*)d_in[6];
  const float* Ww = (const float*)d_in[7];
  // d_in[8] = W_b: constant per-channel shift, canceled by InstanceNorm -> unused
  float* out = (float*)d_out;
  char* ws = (char*)d_ws;
  // workspace layout (~50 MB)
  unsigned short* thetaT = (unsigned short*)(ws);                      // 2 MB
  unsigned short* phiT   = (unsigned short*)(ws + (2ull << 20));       // 2 MB
  unsigned short* gmat   = (unsigned short*)(ws + (4ull << 20));       // 2 MB
  unsigned short* ybuf   = (unsigned short*)(ws + (6ull << 20));       // 2 MB
  float* WyT   = (float*)(ws + (8ull << 20));                          // 8 MB
  float* stat  = (float*)(ws + (16ull << 20));                         // 4 KB
  float* Opart = (float*)(ws + (17ull << 20));                         // 32 MB
  float* lpart = (float*)(ws + (49ull << 20));                         // 512 KB

  hipMemsetAsync(stat, 0, NB * CH * 2 * sizeof(float), stream);
  k_proj<<<dim3(64, 4, 3), 256, 0, stream>>>(x, gw, gb, tw, tb, pw, pb, thetaT, phiT, gmat);
  k_attn<<<dim3(32, 4, 8), 128, 0, stream>>>(thetaT, phiT, gmat, Opart, lpart);
  k_combine<<<dim3((NB * NSP * ICH) / 256), 256, 0, stream>>>(Opart, lpart, ybuf);
  k_wy<<<dim3(16, 4), 256, 0, stream>>>(ybuf, Ww, WyT, stat);
  k_norm<<<dim3(128, 4), 256, 0, stream>>>(WyT, stat, x, out);
}